// Round 12
// baseline (78.515 us; speedup 1.0000x reference)
//
#include <hip/hip_runtime.h>
#include <hip/hip_fp16.h>

#define H 64
#define NA 65536
#define NB 131072
#define NM 16384
#define NC 2048
#define E_AC 65536
#define E_BC 131072
#define E_MC 16384
#define NE_TOT (E_AC + E_BC + E_MC)

#define CAPA 160
#define CAPB 224
#define CAPM 96
#define SLOTB (NC * CAPA)
#define SLOTM (SLOTB + NC * CAPB)
#define SLOT_TOT (SLOTM + NC * CAPM)

typedef __attribute__((ext_vector_type(8))) short bf16x8;
typedef __attribute__((ext_vector_type(4))) float f32x4;

__device__ __forceinline__ float sigmoidf_(float x) { return 1.0f / (1.0f + __expf(-x)); }
__device__ __forceinline__ float softplusf_(float x) {
    return fmaxf(x, 0.0f) + __logf(1.0f + __expf(-fabsf(x)));
}
__device__ __forceinline__ short bf16_of(float f) {
    union { float f; unsigned u; } v; v.f = f;
    unsigned r = (v.u + 0x7fff + ((v.u >> 16) & 1)) >> 16;  // RNE
    return (short)r;
}

// ================= K0: prep0 — zero cnt + weight packs (181 blocks) =================
__global__ __launch_bounds__(256) void prep0_kernel(
    const float* __restrict__ Wa, const float* __restrict__ ba,
    const float* __restrict__ Wb, const float* __restrict__ bb_,
    const float* __restrict__ Wm, const float* __restrict__ bm,
    const float* __restrict__ Wf, const float* __restrict__ bf,
    const float* __restrict__ Ws, const float* __restrict__ bs,
    short* __restrict__ wpA, short* __restrict__ wpM, short* __restrict__ wpC,
    float* __restrict__ biasA, float* __restrict__ biasM, float* __restrict__ biasC,
    __half2* __restrict__ WcB, int* __restrict__ cnt)
{
    int b = blockIdx.x, tid = threadIdx.x;
    for (int i = b * 256 + tid; i < 3 * NC; i += gridDim.x * 256) cnt[i] = 0;

    if (b < 48) {                             // atom composite pack: 96x128, S=3
        int idx = b * 256 + tid;
        int k = idx >> 7, col = idx & 127, c = col & 63;
        const float* WB = ((col < 64) ? Wf : Ws) + (size_t)6 * 2 * H * H + (size_t)H * H;
        float v = 0.0f;
        if (k < 92) {
            const float* a = Wa + (size_t)k * H;
            for (int j = 0; j < H; ++j) v = fmaf(a[j], WB[j * H + c], v);
        }
        int t = col >> 4, lo = col & 15, sm = k >> 5, q = (k >> 3) & 3, e = k & 7;
        wpA[(size_t)(((t * 3 + sm) * 64) + q * 16 + lo) * 8 + e] = bf16_of(v);
    } else if (b < 80) {                      // motif composite pack: 64x128, S=2
        int idx = (b - 48) * 256 + tid;
        int k = idx >> 7, col = idx & 127, c = col & 63;
        const float* WB = ((col < 64) ? Wf : Ws) + (size_t)8 * 2 * H * H + (size_t)H * H;
        float v = 0.0f;
        if (k < 35) {
            const float* a = Wm + (size_t)k * H;
            for (int j = 0; j < H; ++j) v = fmaf(a[j], WB[j * H + c], v);
        }
        int t = col >> 4, lo = col & 15, sm = k >> 5, q = (k >> 3) & 3, e = k & 7;
        wpM[(size_t)(((t * 2 + sm) * 64) + q * 16 + lo) * 8 + e] = bf16_of(v);
    } else if (b < 176) {                     // cell top-half relayout: 3 x 64x128, S=2
        int cu = b - 80;
        int rel = cu >> 5;
        int idx = (cu & 31) * 256 + tid;
        int k = idx >> 7, col = idx & 127, c = col & 63;
        float v = ((col < 64) ? Wf : Ws)[(size_t)(6 + rel) * 2 * H * H + (size_t)k * H + c];
        int t = col >> 4, lo = col & 15, sm = k >> 5, q = (k >> 3) & 3, e = k & 7;
        wpC[(size_t)rel * 8192 + (size_t)(((t * 2 + sm) * 64) + q * 16 + lo) * 8 + e] = bf16_of(v);
    } else if (b == 176) {
        if (tid < 128) {
            int col = tid, c = col & 63;
            const float* WB = ((col < 64) ? Wf : Ws) + (size_t)6 * 2 * H * H + (size_t)H * H;
            float v = 0.0f;
            for (int j = 0; j < H; ++j) v = fmaf(ba[j], WB[j * H + c], v);
            biasA[col] = v;
        }
    } else if (b == 177) {
        if (tid < 128) {
            int col = tid, c = col & 63;
            const float* WB = ((col < 64) ? Wf : Ws) + (size_t)8 * 2 * H * H + (size_t)H * H;
            float v = 0.0f;
            for (int j = 0; j < H; ++j) v = fmaf(bm[j], WB[j * H + c], v);
            biasM[col] = v;
        }
    } else if (b == 178) {
        for (int i = tid; i < 384; i += 256) {
            int rel = i >> 7, col = i & 127, c = col & 63;
            biasC[rel * 128 + col] = ((col < 64) ? bf : bs)[(6 + rel) * H + c];
        }
    } else if (b < 181) {
        int idx = (b - 179) * 256 + tid;
        if (idx < 8 * 64) {
            int k = idx >> 6, col = idx & 63;
            const float* WfB = Wf + (size_t)7 * 2 * H * H + (size_t)H * H;
            const float* WsB = Ws + (size_t)7 * 2 * H * H + (size_t)H * H;
            const float* row = (k < 7) ? (Wb + (size_t)k * H) : bb_;
            float f = 0.0f, s = 0.0f;
            for (int j = 0; j < H; ++j) {
                float rv = row[j];
                f = fmaf(rv, WfB[j * H + col], f);
                s = fmaf(rv, WsB[j * H + col], s);
            }
            WcB[k * 64 + col] = __floats2half2_rn(f, s);
        }
    }
}

// ---------------- G build tile: one wave = 16 rows x 128 cols, no LDS ----------------
template<int K, int S, bool VEC>
__device__ __forceinline__ void gmfma_body(
    int blk, const float* __restrict__ x, const short* __restrict__ wp,
    const float* __restrict__ bias, __half2* __restrict__ g)
{
    int l = threadIdx.x & 63;
    int wv = threadIdx.x >> 6;
    int r0 = (blk * 4 + wv) * 16;
    int lrow = l & 15, q = l >> 4;

    float bF[4], bS[4];
    #pragma unroll
    for (int t = 0; t < 4; ++t) {
        bF[t] = bias[t * 16 + lrow];
        bS[t] = bias[64 + t * 16 + lrow];
    }

    f32x4 acc[8];
    #pragma unroll
    for (int t = 0; t < 8; ++t) acc[t] = (f32x4){0.f, 0.f, 0.f, 0.f};

    const float* xr = x + (size_t)(r0 + lrow) * K;
    #pragma unroll
    for (int s = 0; s < S; ++s) {
        int kb = s * 32 + q * 8;
        bf16x8 afrag;
        if (VEC && kb + 8 <= K) {
            float4 v0 = *(const float4*)(xr + kb);
            float4 v1 = *(const float4*)(xr + kb + 4);
            afrag[0] = bf16_of(v0.x); afrag[1] = bf16_of(v0.y);
            afrag[2] = bf16_of(v0.z); afrag[3] = bf16_of(v0.w);
            afrag[4] = bf16_of(v1.x); afrag[5] = bf16_of(v1.y);
            afrag[6] = bf16_of(v1.z); afrag[7] = bf16_of(v1.w);
        } else {
            #pragma unroll
            for (int e = 0; e < 8; ++e) {
                float xv = 0.0f;
                if (kb + e < K) xv = xr[kb + e];
                afrag[e] = bf16_of(xv);
            }
        }
        #pragma unroll
        for (int t = 0; t < 8; ++t) {
            bf16x8 bt = *(const bf16x8*)(wp + (size_t)((t * S + s) * 64 + l) * 8);
            acc[t] = __builtin_amdgcn_mfma_f32_16x16x32_bf16(afrag, bt, acc[t], 0, 0, 0);
        }
    }

    #pragma unroll
    for (int t = 0; t < 4; ++t)
        #pragma unroll
        for (int r = 0; r < 4; ++r) {
            float fv = acc[t][r] + bF[t];
            float sv = acc[t + 4][r] + bS[t];
            g[(size_t)(r0 + q * 4 + r) * H + t * 16 + lrow] = __floats2half2_rn(fv, sv);
        }
}

// ================= K1: work (1480 blocks, append FIRST, no LDS) =================
__global__ __launch_bounds__(256) void work_kernel(
    const float* __restrict__ xa, const float* __restrict__ xm, const float* __restrict__ xc,
    const short* __restrict__ wpA, const float* __restrict__ biasA,
    const short* __restrict__ wpM, const float* __restrict__ biasM,
    const short* __restrict__ wpC, const float* __restrict__ biasC,
    const int* __restrict__ ea, const int* __restrict__ eb, const int* __restrict__ em,
    int* __restrict__ cnt, int* __restrict__ slots,
    __half2* __restrict__ gA, __half2* __restrict__ gM, __half2* __restrict__ Ccomb)
{
    int b = blockIdx.x, tid = threadIdx.x;
    if (b < 104) {                               // edge append first
        int t0 = b * 256 + tid;
        #pragma unroll
        for (int u2 = 0; u2 < 8; ++u2) {
            int i = t0 + u2 * 26624;
            int r, d, s;
            if (i < E_AC)             { r = 0; s = ea[i];                 d = ea[E_AC + i]; }
            else if (i < E_AC + E_BC) { int k = i - E_AC; r = 1; s = eb[k]; d = eb[E_BC + k]; }
            else                      { int k = i - E_AC - E_BC; r = 2; s = em[k]; d = em[E_MC + k]; }
            int pos = atomicAdd(&cnt[r * NC + d], 1);
            int base, cap;
            if (r == 0)      { base = d * CAPA;         cap = CAPA; }
            else if (r == 1) { base = SLOTB + d * CAPB; cap = CAPB; }
            else             { base = SLOTM + d * CAPM; cap = CAPM; }
            if (pos < cap) slots[base + pos] = s;
        }
    } else if (b < 200) {                        // cell C build via MFMA relayout
        int cu = b - 104;
        int rel = cu >> 5, blk = cu & 31;
        gmfma_body<64, 2, true>(blk, xc, wpC + (size_t)rel * 8192, biasC + rel * 128,
                                Ccomb + (size_t)rel * NC * H);
    } else if (b < 456) {
        gmfma_body<35, 2, false>(b - 200, xm, wpM, biasM, gM);
    } else {
        gmfma_body<92, 3, true>(b - 456, xa, wpA, biasA, gA);
    }
}

// ================= K2: per-cell accumulate + head (2048 blocks x 512) =================
// All slot indices / gather bases forced wave-uniform via readfirstlane -> s_load + saddr.
__global__ __launch_bounds__(512) void cellacc_kernel(
    const __half2* __restrict__ gA, const __half2* __restrict__ gM,
    const float* __restrict__ xb, const __half2* __restrict__ WcB,
    const int* __restrict__ slots, const int* __restrict__ cnt,
    const __half2* __restrict__ Ccomb, const float* __restrict__ xc,
    const float* __restrict__ Wp, const float* __restrict__ bp,
    const float* __restrict__ Wo, const float* __restrict__ bo,
    float* __restrict__ out)
{
    __shared__ float red[8][H];
    __shared__ float vL[H];
    int d = blockIdx.x;
    int lane = threadIdx.x & 63, wv = threadIdx.x >> 6;   // 8 waves
    float acc = 0.0f;

    // ---- atom: gather gA (scalarized indices) ----
    {
        int n = min(cnt[d], CAPA);
        float2 cc = __half22float2(Ccomb[(size_t)d * H + lane]);
        const int* sl = slots + d * CAPA;
        for (int j = wv; j < n; j += 32) {
            float msk[4]; float2 av[4];
            #pragma unroll
            for (int v = 0; v < 4; ++v) {
                int jc = j + 8 * v;
                int jcs = __builtin_amdgcn_readfirstlane((jc < n) ? jc : (n - 1));
                int sidx = sl[jcs];                           // s_load (uniform)
                msk[v] = (jc < n) ? 1.0f : 0.0f;
                av[v] = __half22float2(*(gA + (size_t)sidx * H + lane));  // saddr load
            }
            #pragma unroll
            for (int v = 0; v < 4; ++v)
                acc += msk[v] * (sigmoidf_(cc.x + av[v].x) * softplusf_(cc.y + av[v].y));
        }
    }
    // ---- bond: on-the-fly; feature row via scalar loads (uniform) ----
    {
        int n = min(cnt[NC + d], CAPB);
        float2 cc = __half22float2(Ccomb[(size_t)(NC + d) * H + lane]);
        float wcf[8], wcs[8];
        #pragma unroll
        for (int k = 0; k < 8; ++k) {
            float2 w = __half22float2(WcB[k * 64 + lane]);
            wcf[k] = w.x; wcs[k] = w.y;
        }
        const int* sl = slots + SLOTB + d * CAPB;
        for (int j = wv; j < n; j += 32) {
            float msk[4];
            float xr[4][7];
            #pragma unroll
            for (int v = 0; v < 4; ++v) {
                int jc = j + 8 * v;
                int jcs = __builtin_amdgcn_readfirstlane((jc < n) ? jc : (n - 1));
                int sidx = sl[jcs];                           // s_load (uniform)
                msk[v] = (jc < n) ? 1.0f : 0.0f;
                const float* p = xb + (size_t)sidx * 7;       // uniform -> s_load row
                #pragma unroll
                for (int k = 0; k < 7; ++k) xr[v][k] = p[k];  // SGPRs, not VGPRs
            }
            #pragma unroll
            for (int v = 0; v < 4; ++v) {
                float gf = wcf[7], gs = wcs[7];
                #pragma unroll
                for (int k = 0; k < 7; ++k) {
                    gf = fmaf(xr[v][k], wcf[k], gf);
                    gs = fmaf(xr[v][k], wcs[k], gs);
                }
                acc += msk[v] * (sigmoidf_(cc.x + gf) * softplusf_(cc.y + gs));
            }
        }
    }
    // ---- motif: gather gM (scalarized indices) ----
    {
        int n = min(cnt[2 * NC + d], CAPM);
        float2 cc = __half22float2(Ccomb[(size_t)(2 * NC + d) * H + lane]);
        const int* sl = slots + SLOTM + d * CAPM;
        for (int j = wv; j < n; j += 32) {
            float msk[4]; float2 av[4];
            #pragma unroll
            for (int v = 0; v < 4; ++v) {
                int jc = j + 8 * v;
                int jcs = __builtin_amdgcn_readfirstlane((jc < n) ? jc : (n - 1));
                int sidx = sl[jcs];
                msk[v] = (jc < n) ? 1.0f : 0.0f;
                av[v] = __half22float2(*(gM + (size_t)sidx * H + lane));
            }
            #pragma unroll
            for (int v = 0; v < 4; ++v)
                acc += msk[v] * (sigmoidf_(cc.x + av[v].x) * softplusf_(cc.y + av[v].y));
        }
    }

    red[wv][lane] = acc;
    __syncthreads();
    if (wv == 0) {
        float a = 3.0f * xc[(size_t)d * H + lane];
        #pragma unroll
        for (int w = 0; w < 8; ++w) a += red[w][lane];
        vL[lane] = fmaxf(a, 0.0f);
        __builtin_amdgcn_s_waitcnt(0);   // wave-local LDS drain
        float aj = bp[lane];
        #pragma unroll
        for (int k = 0; k < H; ++k) aj = fmaf(vL[k], Wp[k * H + lane], aj);
        float contrib = softplusf_(aj) * Wo[lane];
        #pragma unroll
        for (int o = 32; o > 0; o >>= 1) contrib += __shfl_down(contrib, o, 64);
        if (lane == 0) out[d] = contrib + bo[0];
    }
}

extern "C" void kernel_launch(void* const* d_in, const int* in_sizes, int n_in,
                              void* d_out, int out_size, void* d_ws, size_t ws_size,
                              hipStream_t stream)
{
    const float* xa = (const float*)d_in[0];
    const float* xb = (const float*)d_in[1];
    const float* xm = (const float*)d_in[2];
    const float* xc = (const float*)d_in[3];
    const float* Wa = (const float*)d_in[4];
    const float* ba = (const float*)d_in[5];
    const float* Wb = (const float*)d_in[6];
    const float* bb_ = (const float*)d_in[7];
    const float* Wm = (const float*)d_in[8];
    const float* bm = (const float*)d_in[9];
    const float* Wf = (const float*)d_in[10];
    const float* bf = (const float*)d_in[11];
    const float* Ws = (const float*)d_in[12];
    const float* bs = (const float*)d_in[13];
    const float* Wp = (const float*)d_in[14];
    const float* bp = (const float*)d_in[15];
    const float* Wo = (const float*)d_in[16];
    const float* bo = (const float*)d_in[17];
    const int* ea = (const int*)d_in[24];
    const int* eb = (const int*)d_in[25];
    const int* em = (const int*)d_in[26];

    // ---- workspace layout (256B-aligned), ~27 MB ----
    char* base = (char*)d_ws;
    size_t o = 0;
    auto alloc = [&](size_t bytes) { char* r = base + o; o = (o + bytes + 255) & ~(size_t)255; return r; };
    int*     cnt   = (int*)    alloc(3 * NC * sizeof(int));
    int*     slots = (int*)    alloc(SLOT_TOT * sizeof(int));
    short*   wpA   = (short*)  alloc(8 * 3 * 64 * 8 * sizeof(short));
    short*   wpM   = (short*)  alloc(8 * 2 * 64 * 8 * sizeof(short));
    short*   wpC   = (short*)  alloc(3 * 8192 * sizeof(short));
    float*   biasA = (float*)  alloc(128 * sizeof(float));
    float*   biasM = (float*)  alloc(128 * sizeof(float));
    float*   biasC = (float*)  alloc(384 * sizeof(float));
    __half2* WcB   = (__half2*)alloc(8 * 64 * sizeof(__half2));
    __half2* Ccomb = (__half2*)alloc((size_t)3 * NC * H * sizeof(__half2));
    __half2* gA    = (__half2*)alloc((size_t)NA * H * sizeof(__half2));
    __half2* gM    = (__half2*)alloc((size_t)NM * H * sizeof(__half2));
    float*   out   = (float*)d_out;

    prep0_kernel<<<181, 256, 0, stream>>>(Wa, ba, Wb, bb_, Wm, bm, Wf, bf, Ws, bs,
                                          wpA, wpM, wpC, biasA, biasM, biasC, WcB, cnt);
    work_kernel<<<1480, 256, 0, stream>>>(xa, xm, xc, wpA, biasA, wpM, biasM, wpC, biasC,
                                          ea, eb, em, cnt, slots, gA, gM, Ccomb);
    cellacc_kernel<<<NC, 512, 0, stream>>>(gA, gM, xb, WcB, slots, cnt, Ccomb,
                                           xc, Wp, bp, Wo, bo, out);
}

// Round 13
// 70.948 us; speedup vs baseline: 1.1067x; 1.1067x over previous
//
#include <hip/hip_runtime.h>
#include <hip/hip_fp16.h>

#define H 64
#define NA 65536
#define NB 131072
#define NM 16384
#define NC 2048
#define E_AC 65536
#define E_BC 131072
#define E_MC 16384
#define NE_TOT (E_AC + E_BC + E_MC)

#define CAPA 160
#define CAPB 224
#define CAPM 96
#define SLOTB (NC * CAPA)
#define SLOTM (SLOTB + NC * CAPB)
#define SLOT_TOT (SLOTM + NC * CAPM)

typedef __attribute__((ext_vector_type(8))) short bf16x8;
typedef __attribute__((ext_vector_type(4))) float f32x4;

__device__ __forceinline__ float sigmoidf_(float x) { return 1.0f / (1.0f + __expf(-x)); }
__device__ __forceinline__ float softplusf_(float x) {
    return fmaxf(x, 0.0f) + __logf(1.0f + __expf(-fabsf(x)));
}
__device__ __forceinline__ short bf16_of(float f) {
    union { float f; unsigned u; } v; v.f = f;
    unsigned r = (v.u + 0x7fff + ((v.u >> 16) & 1)) >> 16;  // RNE
    return (short)r;
}

// ================= K0: prep0 — zero cnt + weight packs (196 blocks) =================
// [0,48): atom pack S=3   [48,80): motif pack S=2   [80,176): cell pack 3x S=2
// [176,192): bond pack S=1   192: biasA  193: biasM  194: biasB  195: biasC
__global__ __launch_bounds__(256) void prep0_kernel(
    const float* __restrict__ Wa, const float* __restrict__ ba,
    const float* __restrict__ Wb, const float* __restrict__ bb_,
    const float* __restrict__ Wm, const float* __restrict__ bm,
    const float* __restrict__ Wf, const float* __restrict__ bf,
    const float* __restrict__ Ws, const float* __restrict__ bs,
    short* __restrict__ wpA, short* __restrict__ wpM, short* __restrict__ wpB,
    short* __restrict__ wpC,
    float* __restrict__ biasA, float* __restrict__ biasM, float* __restrict__ biasB,
    float* __restrict__ biasC, int* __restrict__ cnt)
{
    int b = blockIdx.x, tid = threadIdx.x;
    for (int i = b * 256 + tid; i < 3 * NC; i += gridDim.x * 256) cnt[i] = 0;

    if (b < 48) {                             // atom composite pack: 96x128, S=3
        int idx = b * 256 + tid;
        int k = idx >> 7, col = idx & 127, c = col & 63;
        const float* WB = ((col < 64) ? Wf : Ws) + (size_t)6 * 2 * H * H + (size_t)H * H;
        float v = 0.0f;
        if (k < 92) {
            const float* a = Wa + (size_t)k * H;
            for (int j = 0; j < H; ++j) v = fmaf(a[j], WB[j * H + c], v);
        }
        int t = col >> 4, lo = col & 15, sm = k >> 5, q = (k >> 3) & 3, e = k & 7;
        wpA[(size_t)(((t * 3 + sm) * 64) + q * 16 + lo) * 8 + e] = bf16_of(v);
    } else if (b < 80) {                      // motif composite pack: 64x128, S=2
        int idx = (b - 48) * 256 + tid;
        int k = idx >> 7, col = idx & 127, c = col & 63;
        const float* WB = ((col < 64) ? Wf : Ws) + (size_t)8 * 2 * H * H + (size_t)H * H;
        float v = 0.0f;
        if (k < 35) {
            const float* a = Wm + (size_t)k * H;
            for (int j = 0; j < H; ++j) v = fmaf(a[j], WB[j * H + c], v);
        }
        int t = col >> 4, lo = col & 15, sm = k >> 5, q = (k >> 3) & 3, e = k & 7;
        wpM[(size_t)(((t * 2 + sm) * 64) + q * 16 + lo) * 8 + e] = bf16_of(v);
    } else if (b < 176) {                     // cell top-half relayout: 3 x 64x128, S=2
        int cu = b - 80;
        int rel = cu >> 5;
        int idx = (cu & 31) * 256 + tid;
        int k = idx >> 7, col = idx & 127, c = col & 63;
        float v = ((col < 64) ? Wf : Ws)[(size_t)(6 + rel) * 2 * H * H + (size_t)k * H + c];
        int t = col >> 4, lo = col & 15, sm = k >> 5, q = (k >> 3) & 3, e = k & 7;
        wpC[(size_t)rel * 8192 + (size_t)(((t * 2 + sm) * 64) + q * 16 + lo) * 8 + e] = bf16_of(v);
    } else if (b < 192) {                     // bond composite pack: 32x128, S=1
        int idx = (b - 176) * 256 + tid;      // < 4096
        int k = idx >> 7, col = idx & 127, c = col & 63;
        const float* WB = ((col < 64) ? Wf : Ws) + (size_t)7 * 2 * H * H + (size_t)H * H;
        float v = 0.0f;
        if (k < 7) {
            const float* a = Wb + (size_t)k * H;
            for (int j = 0; j < H; ++j) v = fmaf(a[j], WB[j * H + c], v);
        }
        int t = col >> 4, lo = col & 15, q = (k >> 3) & 3, e = k & 7;
        wpB[(size_t)((t * 64) + q * 16 + lo) * 8 + e] = bf16_of(v);
    } else if (b == 192) {
        if (tid < 128) {
            int col = tid, c = col & 63;
            const float* WB = ((col < 64) ? Wf : Ws) + (size_t)6 * 2 * H * H + (size_t)H * H;
            float v = 0.0f;
            for (int j = 0; j < H; ++j) v = fmaf(ba[j], WB[j * H + c], v);
            biasA[col] = v;
        }
    } else if (b == 193) {
        if (tid < 128) {
            int col = tid, c = col & 63;
            const float* WB = ((col < 64) ? Wf : Ws) + (size_t)8 * 2 * H * H + (size_t)H * H;
            float v = 0.0f;
            for (int j = 0; j < H; ++j) v = fmaf(bm[j], WB[j * H + c], v);
            biasM[col] = v;
        }
    } else if (b == 194) {
        if (tid < 128) {
            int col = tid, c = col & 63;
            const float* WB = ((col < 64) ? Wf : Ws) + (size_t)7 * 2 * H * H + (size_t)H * H;
            float v = 0.0f;
            for (int j = 0; j < H; ++j) v = fmaf(bb_[j], WB[j * H + c], v);
            biasB[col] = v;
        }
    } else {
        for (int i = tid; i < 384; i += 256) {
            int rel = i >> 7, col = i & 127, c = col & 63;
            biasC[rel * 128 + col] = ((col < 64) ? bf : bs)[(6 + rel) * H + c];
        }
    }
}

// ---------------- G build tile: one wave = 16 rows x 128 cols, no LDS ----------------
template<int K, int S, bool VEC>
__device__ __forceinline__ void gmfma_body(
    int blk, const float* __restrict__ x, const short* __restrict__ wp,
    const float* __restrict__ bias, __half2* __restrict__ g)
{
    int l = threadIdx.x & 63;
    int wv = threadIdx.x >> 6;
    int r0 = (blk * 4 + wv) * 16;
    int lrow = l & 15, q = l >> 4;

    float bF[4], bS[4];
    #pragma unroll
    for (int t = 0; t < 4; ++t) {
        bF[t] = bias[t * 16 + lrow];
        bS[t] = bias[64 + t * 16 + lrow];
    }

    f32x4 acc[8];
    #pragma unroll
    for (int t = 0; t < 8; ++t) acc[t] = (f32x4){0.f, 0.f, 0.f, 0.f};

    const float* xr = x + (size_t)(r0 + lrow) * K;
    #pragma unroll
    for (int s = 0; s < S; ++s) {
        int kb = s * 32 + q * 8;
        bf16x8 afrag;
        if (VEC && kb + 8 <= K) {
            float4 v0 = *(const float4*)(xr + kb);
            float4 v1 = *(const float4*)(xr + kb + 4);
            afrag[0] = bf16_of(v0.x); afrag[1] = bf16_of(v0.y);
            afrag[2] = bf16_of(v0.z); afrag[3] = bf16_of(v0.w);
            afrag[4] = bf16_of(v1.x); afrag[5] = bf16_of(v1.y);
            afrag[6] = bf16_of(v1.z); afrag[7] = bf16_of(v1.w);
        } else {
            #pragma unroll
            for (int e = 0; e < 8; ++e) {
                float xv = 0.0f;
                if (kb + e < K) xv = xr[kb + e];
                afrag[e] = bf16_of(xv);
            }
        }
        #pragma unroll
        for (int t = 0; t < 8; ++t) {
            bf16x8 bt = *(const bf16x8*)(wp + (size_t)((t * S + s) * 64 + l) * 8);
            acc[t] = __builtin_amdgcn_mfma_f32_16x16x32_bf16(afrag, bt, acc[t], 0, 0, 0);
        }
    }

    #pragma unroll
    for (int t = 0; t < 4; ++t)
        #pragma unroll
        for (int r = 0; r < 4; ++r) {
            float fv = acc[t][r] + bF[t];
            float sv = acc[t + 4][r] + bS[t];
            g[(size_t)(r0 + q * 4 + r) * H + t * 16 + lrow] = __floats2half2_rn(fv, sv);
        }
}

// ================= K1: work (3528 blocks, append FIRST, no LDS) =================
// [0,104): append  [104,200): cell C  [200,1224): atom G  [1224,3272): bond G
// [3272,3528): motif G.  gAll rows: [0,NA) atom | [NA,NA+NB) bond | [NA+NB,..) motif
__global__ __launch_bounds__(256) void work_kernel(
    const float* __restrict__ xa, const float* __restrict__ xb, const float* __restrict__ xm,
    const float* __restrict__ xc,
    const short* __restrict__ wpA, const float* __restrict__ biasA,
    const short* __restrict__ wpM, const float* __restrict__ biasM,
    const short* __restrict__ wpB, const float* __restrict__ biasB,
    const short* __restrict__ wpC, const float* __restrict__ biasC,
    const int* __restrict__ ea, const int* __restrict__ eb, const int* __restrict__ em,
    int* __restrict__ cnt, int* __restrict__ slots,
    __half2* __restrict__ gAll, __half2* __restrict__ Ccomb)
{
    int b = blockIdx.x, tid = threadIdx.x;
    if (b < 104) {                               // edge append (absolute gAll rows baked in)
        int t0 = b * 256 + tid;
        #pragma unroll
        for (int u2 = 0; u2 < 8; ++u2) {
            int i = t0 + u2 * 26624;
            int r, d, s;
            if (i < E_AC)             { r = 0; s = ea[i];                      d = ea[E_AC + i]; }
            else if (i < E_AC + E_BC) { int k = i - E_AC; r = 1; s = NA + eb[k]; d = eb[E_BC + k]; }
            else                      { int k = i - E_AC - E_BC; r = 2; s = NA + NB + em[k]; d = em[E_MC + k]; }
            int pos = atomicAdd(&cnt[r * NC + d], 1);
            int base, cap;
            if (r == 0)      { base = d * CAPA;         cap = CAPA; }
            else if (r == 1) { base = SLOTB + d * CAPB; cap = CAPB; }
            else             { base = SLOTM + d * CAPM; cap = CAPM; }
            if (pos < cap) slots[base + pos] = s;
        }
    } else if (b < 200) {                        // cell C build via MFMA relayout
        int cu = b - 104;
        int rel = cu >> 5, blk = cu & 31;
        gmfma_body<64, 2, true>(blk, xc, wpC + (size_t)rel * 8192, biasC + rel * 128,
                                Ccomb + (size_t)rel * NC * H);
    } else if (b < 1224) {
        gmfma_body<92, 3, true>(b - 200, xa, wpA, biasA, gAll);
    } else if (b < 3272) {
        gmfma_body<7, 1, false>(b - 1224, xb, wpB, biasB, gAll + (size_t)NA * H);
    } else {
        gmfma_body<35, 2, false>(b - 3272, xm, wpM, biasM, gAll + (size_t)(NA + NB) * H);
    }
}

// ================= K2: per-cell accumulate + head (2048 blocks x 512) =================
// Slot lists staged in LDS; ONE flattened loop over all relations (uniform gather path).
__global__ __launch_bounds__(512) void cellacc_kernel(
    const __half2* __restrict__ gAll,
    const int* __restrict__ slots, const int* __restrict__ cnt,
    const __half2* __restrict__ Ccomb, const float* __restrict__ xc,
    const float* __restrict__ Wp, const float* __restrict__ bp,
    const float* __restrict__ Wo, const float* __restrict__ bo,
    float* __restrict__ out)
{
    __shared__ int   sL[CAPA + CAPB + CAPM];   // 480 ints
    __shared__ float red[8][H];
    __shared__ float vL[H];
    int d = blockIdx.x;
    int tid = threadIdx.x, lane = tid & 63, wv = tid >> 6;   // 8 waves

    int nA = min(cnt[d], CAPA);
    int nB = min(cnt[NC + d], CAPB);
    int nM = min(cnt[2 * NC + d], CAPM);
    for (int i = tid; i < nA; i += 512) sL[i] = slots[d * CAPA + i];
    for (int i = tid; i < nB; i += 512) sL[nA + i] = slots[SLOTB + d * CAPB + i];
    for (int i = tid; i < nM; i += 512) sL[nA + nB + i] = slots[SLOTM + d * CAPM + i];
    float2 ccA = __half22float2(Ccomb[(size_t)d * H + lane]);
    float2 ccB = __half22float2(Ccomb[(size_t)(NC + d) * H + lane]);
    float2 ccM = __half22float2(Ccomb[(size_t)(2 * NC + d) * H + lane]);
    __syncthreads();

    int ntot = nA + nB + nM, nAB = nA + nB;
    float acc = 0.0f;
    int cs = (ntot + 7) >> 3;                  // contiguous chunk per wave
    int p0 = wv * cs, p1 = min(p0 + cs, ntot);
    for (int p = p0; p < p1; p += 4) {
        float ccx[4], ccy[4], msk[4]; float2 av[4];
        #pragma unroll
        for (int v = 0; v < 4; ++v) {
            int pc = p + v;
            msk[v] = (pc < p1) ? 1.0f : 0.0f;
            pc = min(pc, ntot - 1);
            int row = sL[pc];                  // LDS broadcast read
            ccx[v] = (pc < nA) ? ccA.x : (pc < nAB) ? ccB.x : ccM.x;
            ccy[v] = (pc < nA) ? ccA.y : (pc < nAB) ? ccB.y : ccM.y;
            av[v] = __half22float2(gAll[(size_t)row * H + lane]);
        }
        #pragma unroll
        for (int v = 0; v < 4; ++v)
            acc += msk[v] * (sigmoidf_(ccx[v] + av[v].x) * softplusf_(ccy[v] + av[v].y));
    }

    red[wv][lane] = acc;
    __syncthreads();
    if (wv == 0) {
        float a = 3.0f * xc[(size_t)d * H + lane];
        #pragma unroll
        for (int w = 0; w < 8; ++w) a += red[w][lane];
        vL[lane] = fmaxf(a, 0.0f);
        __builtin_amdgcn_s_waitcnt(0);   // wave-local LDS drain
        float aj = bp[lane];
        #pragma unroll
        for (int k = 0; k < H; ++k) aj = fmaf(vL[k], Wp[k * H + lane], aj);
        float contrib = softplusf_(aj) * Wo[lane];
        #pragma unroll
        for (int o = 32; o > 0; o >>= 1) contrib += __shfl_down(contrib, o, 64);
        if (lane == 0) out[d] = contrib + bo[0];
    }
}

extern "C" void kernel_launch(void* const* d_in, const int* in_sizes, int n_in,
                              void* d_out, int out_size, void* d_ws, size_t ws_size,
                              hipStream_t stream)
{
    const float* xa = (const float*)d_in[0];
    const float* xb = (const float*)d_in[1];
    const float* xm = (const float*)d_in[2];
    const float* xc = (const float*)d_in[3];
    const float* Wa = (const float*)d_in[4];
    const float* ba = (const float*)d_in[5];
    const float* Wb = (const float*)d_in[6];
    const float* bb_ = (const float*)d_in[7];
    const float* Wm = (const float*)d_in[8];
    const float* bm = (const float*)d_in[9];
    const float* Wf = (const float*)d_in[10];
    const float* bf = (const float*)d_in[11];
    const float* Ws = (const float*)d_in[12];
    const float* bs = (const float*)d_in[13];
    const float* Wp = (const float*)d_in[14];
    const float* bp = (const float*)d_in[15];
    const float* Wo = (const float*)d_in[16];
    const float* bo = (const float*)d_in[17];
    const int* ea = (const int*)d_in[24];
    const int* eb = (const int*)d_in[25];
    const int* em = (const int*)d_in[26];

    // ---- workspace layout (256B-aligned), ~62 MB ----
    char* base = (char*)d_ws;
    size_t o = 0;
    auto alloc = [&](size_t bytes) { char* r = base + o; o = (o + bytes + 255) & ~(size_t)255; return r; };
    int*     cnt   = (int*)    alloc(3 * NC * sizeof(int));
    int*     slots = (int*)    alloc(SLOT_TOT * sizeof(int));
    short*   wpA   = (short*)  alloc(8 * 3 * 64 * 8 * sizeof(short));
    short*   wpM   = (short*)  alloc(8 * 2 * 64 * 8 * sizeof(short));
    short*   wpB   = (short*)  alloc(8 * 1 * 64 * 8 * sizeof(short));
    short*   wpC   = (short*)  alloc(3 * 8192 * sizeof(short));
    float*   biasA = (float*)  alloc(128 * sizeof(float));
    float*   biasM = (float*)  alloc(128 * sizeof(float));
    float*   biasB = (float*)  alloc(128 * sizeof(float));
    float*   biasC = (float*)  alloc(384 * sizeof(float));
    __half2* Ccomb = (__half2*)alloc((size_t)3 * NC * H * sizeof(__half2));
    __half2* gAll  = (__half2*)alloc((size_t)(NA + NB + NM) * H * sizeof(__half2));  // 54.5 MB
    float*   out   = (float*)d_out;

    prep0_kernel<<<196, 256, 0, stream>>>(Wa, ba, Wb, bb_, Wm, bm, Wf, bf, Ws, bs,
                                          wpA, wpM, wpB, wpC,
                                          biasA, biasM, biasB, biasC, cnt);
    work_kernel<<<3528, 256, 0, stream>>>(xa, xb, xm, xc,
                                          wpA, biasA, wpM, biasM, wpB, biasB, wpC, biasC,
                                          ea, eb, em, cnt, slots, gAll, Ccomb);
    cellacc_kernel<<<NC, 512, 0, stream>>>(gAll, slots, cnt, Ccomb,
                                           xc, Wp, bp, Wo, bo, out);
}